// Round 12
// baseline (200.051 us; speedup 1.0000x reference)
//
#include <hip/hip_runtime.h>
#include <math.h>

#define B_ 16
#define N_ 16384
#define C_ 256
#define H_ 128
#define K_ 11468   // int(16384 * 0.7)
#define G_ ((B_ * N_) / 16)
#define PAIRS_ (G_ / 2)

typedef __attribute__((ext_vector_type(8))) short s16x8;
typedef __attribute__((ext_vector_type(4))) float f32x4;
typedef __attribute__((ext_vector_type(4))) unsigned int u32x4;

__device__ __forceinline__ unsigned short f2bf(float f) {
  unsigned u = __builtin_bit_cast(unsigned, f);
  return (unsigned short)((u + 0x7FFFu + ((u >> 16) & 1u)) >> 16);  // RNE
}
// order-preserving map fp32 -> uint32 (no NaNs expected)
__device__ __forceinline__ unsigned fkey(float f) {
  unsigned u = __builtin_bit_cast(unsigned, f);
  return (u & 0x80000000u) ? ~u : (u | 0x80000000u);
}

// branch-free GELU: Winitzki erf approx (max abs err ~1.2e-4), ~14 VALU ops.
__device__ __forceinline__ float gelu_fast(float h) {
  const float t = 0.5f * h * h;                 // z^2, z = h/sqrt(2)
  const float u = 0.147f * t;
  const float num = t * (1.2732395f + u);       // z^2*(4/pi + a z^2)
  const float den = 1.0f + u;
  const float r = num * __builtin_amdgcn_rcpf(den);
  const float e = __builtin_amdgcn_exp2f(r * -1.44269504f);   // exp(-r)
  const float s = __builtin_amdgcn_sqrtf(fmaxf(1.0f - e, 0.0f));
  const unsigned sgn = __builtin_bit_cast(unsigned, h) & 0x80000000u;
  const float erfv = __builtin_bit_cast(float, __builtin_bit_cast(unsigned, s) | sgn);
  return 0.5f * h * (1.0f + erfv);
}

// ---- w1 fp32 [C][H] -> bf16 [H][C] with XOR-swizzled 16B chunks (LDS-ready) ----
// chunk (r, c16) stored at chunk position (c16 ^ (r & 31)) within row r.
__global__ void k_prep(const float* __restrict__ w1, unsigned short* __restrict__ w1sw) {
  int i = blockIdx.x * blockDim.x + threadIdx.x;  // i = c*H + r over w1
  if (i < C_ * H_) {
    int c = i / H_, r = i % H_;
    int c16 = c >> 3, j = c & 7;
    w1sw[r * 256 + ((c16 ^ (r & 31)) << 3) + j] = f2bf(w1[i]);
  }
}

// ---------------- fused scorer: scores = fc2(gelu(fc1(tokens))) ----------------
// Round-12: PAIR processing — 2 groups (32 tokens) per wave iteration. Each LDS
// B-fragment read feeds TWO MFMAs (halves LDS traffic/token), per-kk work doubles
// so the 4-deep-per-group ring (~8 loads) covers HBM latency, and next-pair
// refills hide under kk>=4 + both epilogues. Accepts 1 wave/SIMD (~165 regs).
__global__ __launch_bounds__(256) void k_score(
    const float* __restrict__ tokens, const unsigned short* __restrict__ w1sw,
    const float* __restrict__ b1, const float* __restrict__ w2,
    const float* __restrict__ b2, float* __restrict__ scores_out) {
  __shared__ unsigned short lds[H_ * C_];  // 64 KB, swizzled bf16 W1^T

  {
    const f32x4* src = reinterpret_cast<const f32x4*>(w1sw);
    f32x4* dst = reinterpret_cast<f32x4*>(lds);
    const int t = threadIdx.x;
#pragma unroll
    for (int i = 0; i < 16; ++i) dst[t + i * 256] = src[t + i * 256];
  }
  __syncthreads();

  const int lane = threadIdx.x & 63;
  const int l15 = lane & 15;
  const int l4 = lane >> 4;
  const int wid = (blockIdx.x * blockDim.x + threadIdx.x) >> 6;
  const int nw = (gridDim.x * blockDim.x) >> 6;

  // prologue: load first pair's kk0..3 into the two 4-deep rings
  f32x4 v0[8], v1[8];
  {
    const float* tc0 = tokens + (size_t)(wid * 32 + l15) * C_ + l4 * 8;
    const float* tc1 = tc0 + 16 * C_;
#pragma unroll
    for (int kk = 0; kk < 4; ++kk) {
      v0[2 * kk] = *reinterpret_cast<const f32x4*>(tc0 + kk * 32);
      v0[2 * kk + 1] = *reinterpret_cast<const f32x4*>(tc0 + kk * 32 + 4);
      v1[2 * kk] = *reinterpret_cast<const f32x4*>(tc1 + kk * 32);
      v1[2 * kk + 1] = *reinterpret_cast<const f32x4*>(tc1 + kk * 32 + 4);
    }
  }

  for (int pr = wid; pr < PAIRS_; pr += nw) {
    const int g0 = 2 * pr;
    const int prn = pr + nw;
    const float* tc0 = tokens + (size_t)(g0 * 16 + l15) * C_ + l4 * 8;
    const float* tc1 = tc0 + 16 * C_;
    const float* tn0 = tokens + (size_t)(2 * prn * 16 + l15) * C_ + l4 * 8;
    const float* tn1 = tn0 + 16 * C_;
    const bool pf = (prn < PAIRS_);

    f32x4 acc0[8], acc1[8];
#pragma unroll
    for (int nb = 0; nb < 8; ++nb) {
      acc0[nb] = (f32x4){0.f, 0.f, 0.f, 0.f};
      acc1[nb] = (f32x4){0.f, 0.f, 0.f, 0.f};
    }

#pragma unroll
    for (int kk = 0; kk < 8; ++kk) {
      const int s0 = (kk & 3) * 2;  // ring slot
      u32x4 a0, a1;
      a0[0] = __builtin_amdgcn_perm(__builtin_bit_cast(unsigned, v0[s0][1]),
                                    __builtin_bit_cast(unsigned, v0[s0][0]), 0x07060302u);
      a0[1] = __builtin_amdgcn_perm(__builtin_bit_cast(unsigned, v0[s0][3]),
                                    __builtin_bit_cast(unsigned, v0[s0][2]), 0x07060302u);
      a0[2] = __builtin_amdgcn_perm(__builtin_bit_cast(unsigned, v0[s0 + 1][1]),
                                    __builtin_bit_cast(unsigned, v0[s0 + 1][0]), 0x07060302u);
      a0[3] = __builtin_amdgcn_perm(__builtin_bit_cast(unsigned, v0[s0 + 1][3]),
                                    __builtin_bit_cast(unsigned, v0[s0 + 1][2]), 0x07060302u);
      a1[0] = __builtin_amdgcn_perm(__builtin_bit_cast(unsigned, v1[s0][1]),
                                    __builtin_bit_cast(unsigned, v1[s0][0]), 0x07060302u);
      a1[1] = __builtin_amdgcn_perm(__builtin_bit_cast(unsigned, v1[s0][3]),
                                    __builtin_bit_cast(unsigned, v1[s0][2]), 0x07060302u);
      a1[2] = __builtin_amdgcn_perm(__builtin_bit_cast(unsigned, v1[s0 + 1][1]),
                                    __builtin_bit_cast(unsigned, v1[s0 + 1][0]), 0x07060302u);
      a1[3] = __builtin_amdgcn_perm(__builtin_bit_cast(unsigned, v1[s0 + 1][3]),
                                    __builtin_bit_cast(unsigned, v1[s0 + 1][2]), 0x07060302u);
      // refill freed slots: kk<4 -> this pair's kk+4; kk>=4 -> next pair's kk-4
      if (kk < 4) {
        v0[s0] = *reinterpret_cast<const f32x4*>(tc0 + (kk + 4) * 32);
        v0[s0 + 1] = *reinterpret_cast<const f32x4*>(tc0 + (kk + 4) * 32 + 4);
        v1[s0] = *reinterpret_cast<const f32x4*>(tc1 + (kk + 4) * 32);
        v1[s0 + 1] = *reinterpret_cast<const f32x4*>(tc1 + (kk + 4) * 32 + 4);
      } else if (pf) {
        v0[s0] = *reinterpret_cast<const f32x4*>(tn0 + (kk - 4) * 32);
        v0[s0 + 1] = *reinterpret_cast<const f32x4*>(tn0 + (kk - 4) * 32 + 4);
        v1[s0] = *reinterpret_cast<const f32x4*>(tn1 + (kk - 4) * 32);
        v1[s0 + 1] = *reinterpret_cast<const f32x4*>(tn1 + (kk - 4) * 32 + 4);
      }
      const int e0 = (((l4 + kk * 4) ^ l15) << 3);  // swizzled chunk (even nb)
#pragma unroll
      for (int nb = 0; nb < 8; ++nb) {
        const int off = (nb & 1) ? (e0 ^ 128) : e0;  // odd nb: row|16 -> toggle bit4
        s16x8 bf = *reinterpret_cast<const s16x8*>(lds + nb * 4096 + l15 * 256 + off);
        acc0[nb] = __builtin_amdgcn_mfma_f32_16x16x32_bf16(
            __builtin_bit_cast(s16x8, a0), bf, acc0[nb], 0, 0, 0);
        acc1[nb] = __builtin_amdgcn_mfma_f32_16x16x32_bf16(
            __builtin_bit_cast(s16x8, a1), bf, acc1[nb], 0, 0, 0);
      }
    }

    // epilogues (identical math/order to round 10 -> bit-identical scores)
#pragma unroll
    for (int half = 0; half < 2; ++half) {
      float p[4] = {0.f, 0.f, 0.f, 0.f};
#pragma unroll
      for (int nb = 0; nb < 8; ++nb) {
        const float b1v = b1[nb * 16 + l15];
        const float w2v = w2[nb * 16 + l15];
#pragma unroll
        for (int r = 0; r < 4; ++r) {
          const float h = (half ? acc1[nb][r] : acc0[nb][r]) + b1v;
          p[r] += gelu_fast(h) * w2v;
        }
      }
      const float b2v = b2[0];
#pragma unroll
      for (int r = 0; r < 4; ++r) {
        float s = p[r];
        s += __shfl_xor(s, 1);
        s += __shfl_xor(s, 2);
        s += __shfl_xor(s, 4);
        s += __shfl_xor(s, 8);
        p[r] = s + b2v;
      }
      if (l15 == 0) {
        const int rb = (g0 + half) * 16 + l4 * 4;
#pragma unroll
        for (int r = 0; r < 4; ++r) scores_out[rb + r] = p[r];
      }
    }
  }
}

// ---------------- block-wide exclusive scan over 1024 threads ----------------
__device__ unsigned block_exscan_1024(unsigned v, volatile unsigned* wsum) {
  const int lane = threadIdx.x & 63;
  const int w = threadIdx.x >> 6;  // 0..15
  unsigned x = v;
#pragma unroll
  for (int d = 1; d < 64; d <<= 1) {
    unsigned t = __shfl_up(x, d);
    if (lane >= d) x += t;
  }
  if (lane == 63) wsum[w] = x;
  __syncthreads();
  if (threadIdx.x == 0) {
    unsigned s = 0;
    for (int i = 0; i < 16; ++i) {
      unsigned t = wsum[i];
      wsum[i] = s;
      s += t;
    }
  }
  __syncthreads();
  unsigned r = wsum[w] + x - v;  // exclusive
  __syncthreads();               // protect wsum for a subsequent call
  return r;
}

// ---------------- per-row top-K via radix select + stable compaction ----------------
__global__ __launch_bounds__(1024) void k_select(const float* __restrict__ scores_f,
                                                 int* __restrict__ kept,
                                                 float* __restrict__ out_idx) {
  __shared__ unsigned hist[256];
  __shared__ unsigned wsum[16];
  __shared__ unsigned sh_prefix, sh_rk;
  const int b = blockIdx.x;
  const int tid = threadIdx.x;
  const float* sp = scores_f + (size_t)b * N_;

  unsigned prefix = 0;
  unsigned rk = K_;  // elements still needed
  for (int pass = 0; pass < 4; ++pass) {
    const int shift = 24 - pass * 8;
    if (tid < 256) hist[tid] = 0;
    __syncthreads();
    const unsigned pmask = pass ? (0xFFFFFFFFu << (shift + 8)) : 0u;
    for (int i = tid; i < N_; i += 1024) {
      unsigned k = fkey(sp[i]);
      if ((k & pmask) == prefix) atomicAdd(&hist[(k >> shift) & 255u], 1u);
    }
    __syncthreads();
    // parallel bin search: suffix-sum via reversed block scan
    unsigned h = (tid < 256) ? hist[255 - tid] : 0u;
    unsigned s = block_exscan_1024(h, wsum);  // s = count of keys in bins > (255-tid)
    if (tid < 256 && s < rk && s + h >= rk) {
      sh_prefix = prefix | ((unsigned)(255 - tid) << shift);
      sh_rk = rk - s;
    }
    __syncthreads();
    prefix = sh_prefix;
    rk = sh_rk;
    __syncthreads();
  }
  const unsigned Tkey = prefix;   // K-th largest key
  const unsigned need = rk;       // how many ==Tkey to keep (lowest indices first)

  // stable compaction in index order; thread owns 16 consecutive indices
  const int i0 = tid * 16;
  unsigned neq = 0;
  for (int j = 0; j < 16; ++j) {
    unsigned k = fkey(sp[i0 + j]);
    neq += (k == Tkey);
  }
  unsigned eq_base = block_exscan_1024(neq, wsum);

  unsigned kcnt = 0;
  {
    unsigned eqr = eq_base;
    for (int j = 0; j < 16; ++j) {
      unsigned k = fkey(sp[i0 + j]);
      bool kp = (k > Tkey) || ((k == Tkey) && (eqr < need));
      eqr += (k == Tkey);
      kcnt += kp;
    }
  }
  unsigned pos = block_exscan_1024(kcnt, wsum);
  {
    unsigned eqr = eq_base;
    for (int j = 0; j < 16; ++j) {
      unsigned k = fkey(sp[i0 + j]);
      bool kp = (k > Tkey) || ((k == Tkey) && (eqr < need));
      eqr += (k == Tkey);
      if (kp) {
        kept[(size_t)b * K_ + pos] = i0 + j;
        out_idx[(size_t)b * K_ + pos] = (float)(i0 + j);
        ++pos;
      }
    }
  }
}

// ---------------- gather kept token rows (fp32 -> fp32) ----------------
__global__ __launch_bounds__(256) void k_gather(const float* __restrict__ tokens,
                                                const int* __restrict__ kept,
                                                float* __restrict__ outp) {
  const int wid = (blockIdx.x * blockDim.x + threadIdx.x) >> 6;  // one wave per row
  const int lane = threadIdx.x & 63;
  if (wid >= B_ * K_) return;
  const int b = wid / K_;
  const int idx = kept[wid];
  const f32x4 v = *reinterpret_cast<const f32x4*>(tokens + ((size_t)b * N_ + idx) * C_ + lane * 4);
  *reinterpret_cast<f32x4*>(outp + (size_t)wid * C_ + lane * 4) = v;
}

extern "C" void kernel_launch(void* const* d_in, const int* in_sizes, int n_in,
                              void* d_out, int out_size, void* d_ws, size_t ws_size,
                              hipStream_t stream) {
  const float* tokens = (const float*)d_in[0];
  const float* w1 = (const float*)d_in[1];
  const float* b1 = (const float*)d_in[2];
  const float* w2 = (const float*)d_in[3];
  const float* b2 = (const float*)d_in[4];

  float* out = (float*)d_out;
  float* out_pruned = out;                                  // B*K*C fp32
  float* out_idx = out + (size_t)B_ * K_ * C_;              // B*K fp32
  float* out_scores = out_idx + (size_t)B_ * K_;            // B*N fp32

  char* ws = (char*)d_ws;
  unsigned short* w1sw = (unsigned short*)ws;               // 64 KB swizzled bf16
  int* kept = (int*)(ws + 0x10000);                         // B*K int32

  k_prep<<<dim3((C_ * H_ + 255) / 256), dim3(256), 0, stream>>>(w1, w1sw);
  k_score<<<dim3(1024), dim3(256), 0, stream>>>(tokens, w1sw, b1, w2, b2, out_scores);
  k_select<<<dim3(B_), dim3(1024), 0, stream>>>(out_scores, kept, out_idx);
  k_gather<<<dim3((B_ * K_ + 3) / 4), dim3(256), 0, stream>>>(tokens, kept, out_pruned);
}

// Round 13
// 168.313 us; speedup vs baseline: 1.1886x; 1.1886x over previous
//
#include <hip/hip_runtime.h>
#include <math.h>

#define B_ 16
#define N_ 16384
#define C_ 256
#define H_ 128
#define K_ 11468   // int(16384 * 0.7)
#define G_ ((B_ * N_) / 16)   // 16384 groups of 16 tokens
#define GPB_ 16               // groups per block
#define NBLK_ (G_ / GPB_)     // 1024 blocks

typedef __attribute__((ext_vector_type(8))) short s16x8;
typedef __attribute__((ext_vector_type(4))) float f32x4;
typedef __attribute__((ext_vector_type(4))) unsigned int u32x4;

__device__ __forceinline__ unsigned short f2bf(float f) {
  unsigned u = __builtin_bit_cast(unsigned, f);
  return (unsigned short)((u + 0x7FFFu + ((u >> 16) & 1u)) >> 16);  // RNE
}
// order-preserving map fp32 -> uint32 (no NaNs expected)
__device__ __forceinline__ unsigned fkey(float f) {
  unsigned u = __builtin_bit_cast(unsigned, f);
  return (u & 0x80000000u) ? ~u : (u | 0x80000000u);
}
// pack two fp32 to two bf16 (truncation) in one v_perm — same bits as rounds 4-12
__device__ __forceinline__ unsigned pk2(float hi, float lo) {
  return __builtin_amdgcn_perm(__builtin_bit_cast(unsigned, hi),
                               __builtin_bit_cast(unsigned, lo), 0x07060302u);
}

// branch-free GELU: Winitzki erf approx (max abs err ~1.2e-4), ~14 VALU ops.
__device__ __forceinline__ float gelu_fast(float h) {
  const float t = 0.5f * h * h;                 // z^2, z = h/sqrt(2)
  const float u = 0.147f * t;
  const float num = t * (1.2732395f + u);       // z^2*(4/pi + a z^2)
  const float den = 1.0f + u;
  const float r = num * __builtin_amdgcn_rcpf(den);
  const float e = __builtin_amdgcn_exp2f(r * -1.44269504f);   // exp(-r)
  const float s = __builtin_amdgcn_sqrtf(fmaxf(1.0f - e, 0.0f));
  const unsigned sgn = __builtin_bit_cast(unsigned, h) & 0x80000000u;
  const float erfv = __builtin_bit_cast(float, __builtin_bit_cast(unsigned, s) | sgn);
  return 0.5f * h * (1.0f + erfv);
}

// ---- w1 fp32 [C][H] -> plain bf16 transpose w1t[H][C] (no swizzle needed now) ----
__global__ void k_prep(const float* __restrict__ w1, unsigned short* __restrict__ w1t) {
  int i = blockIdx.x * blockDim.x + threadIdx.x;  // i = c*H + h over w1
  if (i < C_ * H_) {
    int c = i / H_, h = i % H_;
    w1t[h * C_ + c] = f2bf(w1[i]);
  }
}

// ---------------- fused scorer: scores = fc2(gelu(fc1(tokens))) ----------------
// Cooperative block: 4 waves share one 16-token group. W1 in registers (wave w
// owns hidden blocks 2w,2w+1 = 64 VGPRs), tokens staged through double-buffered
// LDS in fragment order ([kk][lane] -> conflict-free ds_read_b128), packed to
// bf16 ONCE per block. Loads for g+1 issued before g's MFMAs (issue-early /
// write-late). Partial scores combined via tiny LDS array.
__global__ __launch_bounds__(256) void k_score(
    const float* __restrict__ tokens, const unsigned short* __restrict__ w1t,
    const float* __restrict__ b1, const float* __restrict__ w2,
    const float* __restrict__ b2, float* __restrict__ scores_out) {
  __shared__ unsigned short lds_a[2][8 * 64 * 8];  // 2 x 8KB bf16 A-fragments
  __shared__ float lds_c[4][16];                   // per-wave partial scores

  const int tid = threadIdx.x;
  const int lane = tid & 63;
  const int l15 = lane & 15;
  const int l4 = lane >> 4;
  const int w = tid >> 6;  // wave 0..3

  // W1 fragments for this wave's hidden blocks nb=2w (row0) and nb=2w+1 (row1)
  s16x8 bfr0[8], bfr1[8];
  const int row0 = (2 * w) * 16 + l15;
  const int row1 = row0 + 16;
#pragma unroll
  for (int kk = 0; kk < 8; ++kk) {
    bfr0[kk] = *reinterpret_cast<const s16x8*>(w1t + row0 * 256 + (l4 + 4 * kk) * 8);
    bfr1[kk] = *reinterpret_cast<const s16x8*>(w1t + row1 * 256 + (l4 + 4 * kk) * 8);
  }
  const float b1v0 = b1[row0], b1v1 = b1[row1];
  const float w2v0 = w2[row0], w2v1 = w2[row1];
  const float b2v = b2[0];

  // staging role: thread owns token row sr, fp32 16-float chunk sq
  const int sr = tid >> 4;
  const int sq = tid & 15;

  const int g0 = blockIdx.x * GPB_;
  f32x4 vv[4];

  // prologue: stage group g0 into buffer 0
  {
    const float* p = tokens + ((size_t)(g0 * 16 + sr)) * 256 + sq * 16;
#pragma unroll
    for (int i2 = 0; i2 < 4; ++i2) vv[i2] = *reinterpret_cast<const f32x4*>(p + 4 * i2);
#pragma unroll
    for (int j = 0; j < 2; ++j) {
      u32x4 o;
      o[0] = pk2(vv[2 * j][1], vv[2 * j][0]);
      o[1] = pk2(vv[2 * j][3], vv[2 * j][2]);
      o[2] = pk2(vv[2 * j + 1][1], vv[2 * j + 1][0]);
      o[3] = pk2(vv[2 * j + 1][3], vv[2 * j + 1][2]);
      const int c = 2 * sq + j;  // bf16 8-elt chunk index; kk=c>>2, l4'=c&3
      *reinterpret_cast<u32x4*>(&lds_a[0][((c >> 2) * 64 + (c & 3) * 16 + sr) * 8]) = o;
    }
  }
  __syncthreads();

  int cur = 0;
  for (int i = 0; i < GPB_; ++i) {
    const int g = g0 + i;
    // issue next group's loads EARLY; they land during MFMAs + barriers
    if (i + 1 < GPB_) {
      const float* p = tokens + ((size_t)((g + 1) * 16 + sr)) * 256 + sq * 16;
#pragma unroll
      for (int i2 = 0; i2 < 4; ++i2) vv[i2] = *reinterpret_cast<const f32x4*>(p + 4 * i2);
    }

    // compute: 16 MFMAs (8 kk x 2 nb), A shared from LDS, B from registers
    f32x4 acc0 = (f32x4){0.f, 0.f, 0.f, 0.f};
    f32x4 acc1 = (f32x4){0.f, 0.f, 0.f, 0.f};
#pragma unroll
    for (int kk = 0; kk < 8; ++kk) {
      s16x8 a = *reinterpret_cast<const s16x8*>(&lds_a[cur][(kk * 64 + lane) * 8]);
      acc0 = __builtin_amdgcn_mfma_f32_16x16x32_bf16(a, bfr0[kk], acc0, 0, 0, 0);
      acc1 = __builtin_amdgcn_mfma_f32_16x16x32_bf16(a, bfr1[kk], acc1, 0, 0, 0);
    }

    // partial epilogue for this wave's 2 hidden blocks; reduce over l15
    float p4[4];
#pragma unroll
    for (int rr = 0; rr < 4; ++rr) {
      float s = gelu_fast(acc0[rr] + b1v0) * w2v0 + gelu_fast(acc1[rr] + b1v1) * w2v1;
      s += __shfl_xor(s, 1);
      s += __shfl_xor(s, 2);
      s += __shfl_xor(s, 4);
      s += __shfl_xor(s, 8);
      p4[rr] = s;  // score partial for token l4*4+rr
    }
    if (l15 == 0) {
#pragma unroll
      for (int rr = 0; rr < 4; ++rr) lds_c[w][l4 * 4 + rr] = p4[rr];
    }
    __syncthreads();  // (A) partials visible; all reads of lds_a[cur] done

    if (tid < 16) {
      scores_out[g * 16 + tid] =
          lds_c[0][tid] + lds_c[1][tid] + lds_c[2][tid] + lds_c[3][tid] + b2v;
    }
    // write-late: pack and store next group's fragments into the other buffer
    if (i + 1 < GPB_) {
#pragma unroll
      for (int j = 0; j < 2; ++j) {
        u32x4 o;
        o[0] = pk2(vv[2 * j][1], vv[2 * j][0]);
        o[1] = pk2(vv[2 * j][3], vv[2 * j][2]);
        o[2] = pk2(vv[2 * j + 1][1], vv[2 * j + 1][0]);
        o[3] = pk2(vv[2 * j + 1][3], vv[2 * j + 1][2]);
        const int c = 2 * sq + j;
        *reinterpret_cast<u32x4*>(
            &lds_a[cur ^ 1][((c >> 2) * 64 + (c & 3) * 16 + sr) * 8]) = o;
      }
    }
    __syncthreads();  // (B) staging complete; lds_c consumed
    cur ^= 1;
  }
}

// ---------------- block-wide exclusive scan over 1024 threads ----------------
__device__ unsigned block_exscan_1024(unsigned v, volatile unsigned* wsum) {
  const int lane = threadIdx.x & 63;
  const int w = threadIdx.x >> 6;  // 0..15
  unsigned x = v;
#pragma unroll
  for (int d = 1; d < 64; d <<= 1) {
    unsigned t = __shfl_up(x, d);
    if (lane >= d) x += t;
  }
  if (lane == 63) wsum[w] = x;
  __syncthreads();
  if (threadIdx.x == 0) {
    unsigned s = 0;
    for (int i = 0; i < 16; ++i) {
      unsigned t = wsum[i];
      wsum[i] = s;
      s += t;
    }
  }
  __syncthreads();
  unsigned r = wsum[w] + x - v;  // exclusive
  __syncthreads();               // protect wsum for a subsequent call
  return r;
}

// ---------------- per-row top-K via radix select + stable compaction ----------------
__global__ __launch_bounds__(1024) void k_select(const float* __restrict__ scores_f,
                                                 int* __restrict__ kept,
                                                 float* __restrict__ out_idx) {
  __shared__ unsigned hist[256];
  __shared__ unsigned wsum[16];
  __shared__ unsigned sh_prefix, sh_rk;
  const int b = blockIdx.x;
  const int tid = threadIdx.x;
  const float* sp = scores_f + (size_t)b * N_;

  unsigned prefix = 0;
  unsigned rk = K_;  // elements still needed
  for (int pass = 0; pass < 4; ++pass) {
    const int shift = 24 - pass * 8;
    if (tid < 256) hist[tid] = 0;
    __syncthreads();
    const unsigned pmask = pass ? (0xFFFFFFFFu << (shift + 8)) : 0u;
    for (int i = tid; i < N_; i += 1024) {
      unsigned k = fkey(sp[i]);
      if ((k & pmask) == prefix) atomicAdd(&hist[(k >> shift) & 255u], 1u);
    }
    __syncthreads();
    // parallel bin search: suffix-sum via reversed block scan
    unsigned h = (tid < 256) ? hist[255 - tid] : 0u;
    unsigned s = block_exscan_1024(h, wsum);  // s = count of keys in bins > (255-tid)
    if (tid < 256 && s < rk && s + h >= rk) {
      sh_prefix = prefix | ((unsigned)(255 - tid) << shift);
      sh_rk = rk - s;
    }
    __syncthreads();
    prefix = sh_prefix;
    rk = sh_rk;
    __syncthreads();
  }
  const unsigned Tkey = prefix;   // K-th largest key
  const unsigned need = rk;       // how many ==Tkey to keep (lowest indices first)

  // stable compaction in index order; thread owns 16 consecutive indices
  const int i0 = tid * 16;
  unsigned neq = 0;
  for (int j = 0; j < 16; ++j) {
    unsigned k = fkey(sp[i0 + j]);
    neq += (k == Tkey);
  }
  unsigned eq_base = block_exscan_1024(neq, wsum);

  unsigned kcnt = 0;
  {
    unsigned eqr = eq_base;
    for (int j = 0; j < 16; ++j) {
      unsigned k = fkey(sp[i0 + j]);
      bool kp = (k > Tkey) || ((k == Tkey) && (eqr < need));
      eqr += (k == Tkey);
      kcnt += kp;
    }
  }
  unsigned pos = block_exscan_1024(kcnt, wsum);
  {
    unsigned eqr = eq_base;
    for (int j = 0; j < 16; ++j) {
      unsigned k = fkey(sp[i0 + j]);
      bool kp = (k > Tkey) || ((k == Tkey) && (eqr < need));
      eqr += (k == Tkey);
      if (kp) {
        kept[(size_t)b * K_ + pos] = i0 + j;
        out_idx[(size_t)b * K_ + pos] = (float)(i0 + j);
        ++pos;
      }
    }
  }
}

// ---------------- gather kept token rows (fp32 -> fp32) ----------------
__global__ __launch_bounds__(256) void k_gather(const float* __restrict__ tokens,
                                                const int* __restrict__ kept,
                                                float* __restrict__ outp) {
  const int wid = (blockIdx.x * blockDim.x + threadIdx.x) >> 6;  // one wave per row
  const int lane = threadIdx.x & 63;
  if (wid >= B_ * K_) return;
  const int b = wid / K_;
  const int idx = kept[wid];
  const f32x4 v = *reinterpret_cast<const f32x4*>(tokens + ((size_t)b * N_ + idx) * C_ + lane * 4);
  *reinterpret_cast<f32x4*>(outp + (size_t)wid * C_ + lane * 4) = v;
}

extern "C" void kernel_launch(void* const* d_in, const int* in_sizes, int n_in,
                              void* d_out, int out_size, void* d_ws, size_t ws_size,
                              hipStream_t stream) {
  const float* tokens = (const float*)d_in[0];
  const float* w1 = (const float*)d_in[1];
  const float* b1 = (const float*)d_in[2];
  const float* w2 = (const float*)d_in[3];
  const float* b2 = (const float*)d_in[4];

  float* out = (float*)d_out;
  float* out_pruned = out;                                  // B*K*C fp32
  float* out_idx = out + (size_t)B_ * K_ * C_;              // B*K fp32
  float* out_scores = out_idx + (size_t)B_ * K_;            // B*N fp32

  char* ws = (char*)d_ws;
  unsigned short* w1t = (unsigned short*)ws;                // 64 KB plain bf16 W1^T
  int* kept = (int*)(ws + 0x10000);                         // B*K int32

  k_prep<<<dim3((C_ * H_ + 255) / 256), dim3(256), 0, stream>>>(w1, w1t);
  k_score<<<dim3(NBLK_), dim3(256), 0, stream>>>(tokens, w1t, b1, w2, b2, out_scores);
  k_select<<<dim3(B_), dim3(1024), 0, stream>>>(out_scores, kept, out_idx);
  k_gather<<<dim3((B_ * K_ + 3) / 4), dim3(256), 0, stream>>>(tokens, kept, out_pruned);
}